// Round 1
// baseline (1247.645 us; speedup 1.0000x reference)
//
#include <hip/hip_runtime.h>

#define N_NODES 50000
#define D 128
#define EDGES 640000
#define BM 64
#define BK 16

// ---------------------------------------------------------------------------
// Kernel 1: scatter-add of gathered neighbor features.
// 32 threads per edge; each thread float4-loads 4 features of x[col[e]] and
// atomicAdd's them into sum[row[e]]. Lane 0 of each edge bumps the count.
// ---------------------------------------------------------------------------
__global__ __launch_bounds__(256) void scatter_kernel(
    const float* __restrict__ x,
    const int* __restrict__ row,
    const int* __restrict__ col,
    float* __restrict__ sum,
    float* __restrict__ cnt) {
    int tid = blockIdx.x * blockDim.x + threadIdx.x;
    int e = tid >> 5;
    int part = tid & 31;
    if (e >= EDGES) return;
    int r = row[e];
    int c = col[e];
    const float4* xs = (const float4*)(x + (size_t)c * D);
    float4 v = xs[part];
    float* dst = sum + (size_t)r * D + part * 4;
    atomicAdd(dst + 0, v.x);
    atomicAdd(dst + 1, v.y);
    atomicAdd(dst + 2, v.z);
    atomicAdd(dst + 3, v.w);
    if (part == 0) atomicAdd(cnt + r, 1.0f);
}

// ---------------------------------------------------------------------------
// Kernel 2: sum -> mean in place.  i indexes float4s of the [N,128] buffer.
// ---------------------------------------------------------------------------
__global__ __launch_bounds__(256) void finalize_kernel(
    float* __restrict__ sum, const float* __restrict__ cnt) {
    int i = blockIdx.x * blockDim.x + threadIdx.x;
    if (i >= N_NODES * (D / 4)) return;
    int node = i >> 5;  // i*4 >> 7
    float inv = 1.0f / (cnt[node] + 1e-8f);
    float4* p = (float4*)sum;
    float4 v = p[i];
    v.x *= inv; v.y *= inv; v.z *= inv; v.w *= inv;
    p[i] = v;
}

// ---------------------------------------------------------------------------
// Kernel 3: out = relu([x | mean] @ W^T + b)
// M=50000, K=256, Nout=128.  Tile: BM=64 rows x full 128 cols, BK=16.
// 256 threads; thread (ty,tx) computes 8 rows x 4 cols.
// ---------------------------------------------------------------------------
__global__ __launch_bounds__(256) void gemm_kernel(
    const float* __restrict__ x, const float* __restrict__ mean,
    const float* __restrict__ W, const float* __restrict__ bias,
    float* __restrict__ out) {
    __shared__ float As[BK][BM];
    __shared__ float Bs[BK][128];
    int t = threadIdx.x;
    int tx = t & 31;   // 32 col groups of 4 -> 128 cols
    int ty = t >> 5;   // 8 row groups of 8 -> 64 rows
    int block_row = blockIdx.x * BM;

    float acc[8][4] = {};

    for (int k0 = 0; k0 < 2 * D; k0 += BK) {
        // A tile: 64 nodes x 16 k.  Thread loads float4 along k of one node.
        {
            int m = t >> 2;          // 0..63
            int kk = (t & 3) * 4;    // 0,4,8,12
            int node = block_row + m;
            if (node >= N_NODES) node = N_NODES - 1;  // clamp; stores guarded
            int kg = k0 + kk;
            const float* src = (kg < D) ? (x + (size_t)node * D + kg)
                                        : (mean + (size_t)node * D + (kg - D));
            float4 v = *(const float4*)src;
            As[kk + 0][m] = v.x;
            As[kk + 1][m] = v.y;
            As[kk + 2][m] = v.z;
            As[kk + 3][m] = v.w;
        }
        // B tile: Bs[k][n] = W[n][k0+k].  Thread loads 8 consecutive k of row n.
        {
            int n = t >> 1;          // 0..127
            int kk = (t & 1) * 8;    // 0 or 8
            const float* src = W + (size_t)n * (2 * D) + k0 + kk;
            float4 v0 = *(const float4*)src;
            float4 v1 = *(const float4*)(src + 4);
            Bs[kk + 0][n] = v0.x;
            Bs[kk + 1][n] = v0.y;
            Bs[kk + 2][n] = v0.z;
            Bs[kk + 3][n] = v0.w;
            Bs[kk + 4][n] = v1.x;
            Bs[kk + 5][n] = v1.y;
            Bs[kk + 6][n] = v1.z;
            Bs[kk + 7][n] = v1.w;
        }
        __syncthreads();
        #pragma unroll
        for (int kk = 0; kk < BK; ++kk) {
            float a[8], bv[4];
            #pragma unroll
            for (int i = 0; i < 8; ++i) a[i] = As[kk][ty * 8 + i];
            #pragma unroll
            for (int j = 0; j < 4; ++j) bv[j] = Bs[kk][tx * 4 + j];
            #pragma unroll
            for (int i = 0; i < 8; ++i)
                #pragma unroll
                for (int j = 0; j < 4; ++j)
                    acc[i][j] += a[i] * bv[j];
        }
        __syncthreads();
    }

    float bv[4];
    #pragma unroll
    for (int j = 0; j < 4; ++j) bv[j] = bias[tx * 4 + j];
    #pragma unroll
    for (int i = 0; i < 8; ++i) {
        int node = block_row + ty * 8 + i;
        if (node < N_NODES) {
            float4 o;
            o.x = fmaxf(acc[i][0] + bv[0], 0.0f);
            o.y = fmaxf(acc[i][1] + bv[1], 0.0f);
            o.z = fmaxf(acc[i][2] + bv[2], 0.0f);
            o.w = fmaxf(acc[i][3] + bv[3], 0.0f);
            *(float4*)(out + (size_t)node * D + tx * 4) = o;
        }
    }
}

extern "C" void kernel_launch(void* const* d_in, const int* in_sizes, int n_in,
                              void* d_out, int out_size, void* d_ws, size_t ws_size,
                              hipStream_t stream) {
    const float* x    = (const float*)d_in[0];
    const int*   ei   = (const int*)d_in[1];   // [2, E] int32: row = ei, col = ei+E
    const float* W    = (const float*)d_in[2];
    const float* bias = (const float*)d_in[3];
    float* out = (float*)d_out;

    float* sum = (float*)d_ws;                       // [N, 128]
    float* cnt = sum + (size_t)N_NODES * D;          // [N]

    hipMemsetAsync(d_ws, 0, ((size_t)N_NODES * D + N_NODES) * sizeof(float), stream);

    int scatter_threads = EDGES * 32;
    scatter_kernel<<<(scatter_threads + 255) / 256, 256, 0, stream>>>(
        x, ei, ei + EDGES, sum, cnt);

    int fin_threads = N_NODES * (D / 4);
    finalize_kernel<<<(fin_threads + 255) / 256, 256, 0, stream>>>(sum, cnt);

    gemm_kernel<<<(N_NODES + BM - 1) / BM, 256, 0, stream>>>(x, sum, W, bias, out);
}

// Round 2
// 250.613 us; speedup vs baseline: 4.9784x; 4.9784x over previous
//
#include <hip/hip_runtime.h>

#define N_NODES 50000
#define D 128
#define EDGES 640000
#define BM 64
#define BK 16
#define SCAN_CHUNK 256
#define NUM_CHUNKS ((N_NODES + SCAN_CHUNK - 1) / SCAN_CHUNK)  // 196

// ===========================================================================
// CSR build path (no heavy atomics)
// ===========================================================================

// deg[r] += 1 per edge
__global__ __launch_bounds__(256) void deg_kernel(
    const int* __restrict__ row, int* __restrict__ deg) {
    int e = blockIdx.x * blockDim.x + threadIdx.x;
    if (e < EDGES) atomicAdd(&deg[row[e]], 1);
}

// partial[b] = sum of deg over chunk b
__global__ __launch_bounds__(SCAN_CHUNK) void chunk_sum_kernel(
    const int* __restrict__ deg, int* __restrict__ partial) {
    __shared__ int s[SCAN_CHUNK];
    int t = threadIdx.x;
    int i = blockIdx.x * SCAN_CHUNK + t;
    s[t] = (i < N_NODES) ? deg[i] : 0;
    __syncthreads();
    for (int off = SCAN_CHUNK / 2; off > 0; off >>= 1) {
        if (t < off) s[t] += s[t + off];
        __syncthreads();
    }
    if (t == 0) partial[blockIdx.x] = s[0];
}

// scanned[b] = exclusive prefix sum of partial[0..b)
__global__ __launch_bounds__(SCAN_CHUNK) void scan_partials_kernel(
    const int* __restrict__ partial, int* __restrict__ scanned) {
    __shared__ int s[SCAN_CHUNK];
    int t = threadIdx.x;
    int v = (t < NUM_CHUNKS) ? partial[t] : 0;
    s[t] = v;
    __syncthreads();
    for (int off = 1; off < SCAN_CHUNK; off <<= 1) {
        int add = (t >= off) ? s[t - off] : 0;
        __syncthreads();
        s[t] += add;
        __syncthreads();
    }
    if (t < NUM_CHUNKS) scanned[t] = s[t] - v;  // exclusive
}

// offsets[i] = global exclusive prefix of deg (start position of node i)
__global__ __launch_bounds__(SCAN_CHUNK) void chunk_scan_kernel(
    const int* __restrict__ deg, const int* __restrict__ scanned,
    int* __restrict__ offsets) {
    __shared__ int s[SCAN_CHUNK];
    int t = threadIdx.x;
    int i = blockIdx.x * SCAN_CHUNK + t;
    int v = (i < N_NODES) ? deg[i] : 0;
    s[t] = v;
    __syncthreads();
    for (int off = 1; off < SCAN_CHUNK; off <<= 1) {
        int add = (t >= off) ? s[t - off] : 0;
        __syncthreads();
        s[t] += add;
        __syncthreads();
    }
    if (i < N_NODES) offsets[i] = s[t] - v + scanned[blockIdx.x];
}

// csr_col[pos] = col[e], pos from self-incrementing offsets.
// After this, offsets[i] == start of node i+1 (inclusive-scan semantics).
__global__ __launch_bounds__(256) void fill_kernel(
    const int* __restrict__ row, const int* __restrict__ col,
    int* __restrict__ offsets, int* __restrict__ csr_col) {
    int e = blockIdx.x * blockDim.x + threadIdx.x;
    if (e >= EDGES) return;
    int pos = atomicAdd(&offsets[row[e]], 1);
    csr_col[pos] = col[e];
}

// mean[n] = (1/(deg+1e-8)) * sum_{e in CSR[n]} x[csr_col[e]]
// 32 threads per node, one float4 (4 features) per thread.
__global__ __launch_bounds__(256) void gather_mean_kernel(
    const float* __restrict__ x, const int* __restrict__ csr_col,
    const int* __restrict__ offsets, float* __restrict__ mean) {
    int tid = blockIdx.x * blockDim.x + threadIdx.x;
    int node = tid >> 5;
    int part = tid & 31;
    if (node >= N_NODES) return;
    int start = (node == 0) ? 0 : offsets[node - 1];
    int end = offsets[node];
    float4 acc = {0.f, 0.f, 0.f, 0.f};
    for (int e = start; e < end; ++e) {
        int c = csr_col[e];
        float4 v = ((const float4*)(x + (size_t)c * D))[part];
        acc.x += v.x; acc.y += v.y; acc.z += v.z; acc.w += v.w;
    }
    float inv = 1.0f / ((float)(end - start) + 1e-8f);
    acc.x *= inv; acc.y *= inv; acc.z *= inv; acc.w *= inv;
    ((float4*)(mean + (size_t)node * D))[part] = acc;
}

// ===========================================================================
// Fallback path (round-1 atomic scatter) if ws_size is too small
// ===========================================================================
__global__ __launch_bounds__(256) void scatter_kernel(
    const float* __restrict__ x, const int* __restrict__ row,
    const int* __restrict__ col, float* __restrict__ sum,
    float* __restrict__ cnt) {
    int tid = blockIdx.x * blockDim.x + threadIdx.x;
    int e = tid >> 5;
    int part = tid & 31;
    if (e >= EDGES) return;
    int r = row[e];
    int c = col[e];
    float4 v = ((const float4*)(x + (size_t)c * D))[part];
    float* dst = sum + (size_t)r * D + part * 4;
    atomicAdd(dst + 0, v.x);
    atomicAdd(dst + 1, v.y);
    atomicAdd(dst + 2, v.z);
    atomicAdd(dst + 3, v.w);
    if (part == 0) atomicAdd(cnt + r, 1.0f);
}

__global__ __launch_bounds__(256) void finalize_kernel(
    float* __restrict__ sum, const float* __restrict__ cnt) {
    int i = blockIdx.x * blockDim.x + threadIdx.x;
    if (i >= N_NODES * (D / 4)) return;
    int node = i >> 5;
    float inv = 1.0f / (cnt[node] + 1e-8f);
    float4* p = (float4*)sum;
    float4 v = p[i];
    v.x *= inv; v.y *= inv; v.z *= inv; v.w *= inv;
    p[i] = v;
}

// ===========================================================================
// GEMM: out = relu([x | mean] @ W^T + b)
// ===========================================================================
__global__ __launch_bounds__(256) void gemm_kernel(
    const float* __restrict__ x, const float* __restrict__ mean,
    const float* __restrict__ W, const float* __restrict__ bias,
    float* __restrict__ out) {
    __shared__ float As[BK][BM];
    __shared__ float Bs[BK][128];
    int t = threadIdx.x;
    int tx = t & 31;
    int ty = t >> 5;
    int block_row = blockIdx.x * BM;

    float acc[8][4] = {};

    for (int k0 = 0; k0 < 2 * D; k0 += BK) {
        {
            int m = t >> 2;
            int kk = (t & 3) * 4;
            int node = block_row + m;
            if (node >= N_NODES) node = N_NODES - 1;
            int kg = k0 + kk;
            const float* src = (kg < D) ? (x + (size_t)node * D + kg)
                                        : (mean + (size_t)node * D + (kg - D));
            float4 v = *(const float4*)src;
            As[kk + 0][m] = v.x;
            As[kk + 1][m] = v.y;
            As[kk + 2][m] = v.z;
            As[kk + 3][m] = v.w;
        }
        {
            int n = t >> 1;
            int kk = (t & 1) * 8;
            const float* src = W + (size_t)n * (2 * D) + k0 + kk;
            float4 v0 = *(const float4*)src;
            float4 v1 = *(const float4*)(src + 4);
            Bs[kk + 0][n] = v0.x;
            Bs[kk + 1][n] = v0.y;
            Bs[kk + 2][n] = v0.z;
            Bs[kk + 3][n] = v0.w;
            Bs[kk + 4][n] = v1.x;
            Bs[kk + 5][n] = v1.y;
            Bs[kk + 6][n] = v1.z;
            Bs[kk + 7][n] = v1.w;
        }
        __syncthreads();
        #pragma unroll
        for (int kk = 0; kk < BK; ++kk) {
            float a[8], bv[4];
            #pragma unroll
            for (int i = 0; i < 8; ++i) a[i] = As[kk][ty * 8 + i];
            #pragma unroll
            for (int j = 0; j < 4; ++j) bv[j] = Bs[kk][tx * 4 + j];
            #pragma unroll
            for (int i = 0; i < 8; ++i)
                #pragma unroll
                for (int j = 0; j < 4; ++j)
                    acc[i][j] += a[i] * bv[j];
        }
        __syncthreads();
    }

    float bv[4];
    #pragma unroll
    for (int j = 0; j < 4; ++j) bv[j] = bias[tx * 4 + j];
    #pragma unroll
    for (int i = 0; i < 8; ++i) {
        int node = block_row + ty * 8 + i;
        if (node < N_NODES) {
            float4 o;
            o.x = fmaxf(acc[i][0] + bv[0], 0.0f);
            o.y = fmaxf(acc[i][1] + bv[1], 0.0f);
            o.z = fmaxf(acc[i][2] + bv[2], 0.0f);
            o.w = fmaxf(acc[i][3] + bv[3], 0.0f);
            *(float4*)(out + (size_t)node * D + tx * 4) = o;
        }
    }
}

extern "C" void kernel_launch(void* const* d_in, const int* in_sizes, int n_in,
                              void* d_out, int out_size, void* d_ws, size_t ws_size,
                              hipStream_t stream) {
    const float* x    = (const float*)d_in[0];
    const int*   ei   = (const int*)d_in[1];   // [2, E] int32
    const float* W    = (const float*)d_in[2];
    const float* bias = (const float*)d_in[3];
    float* out = (float*)d_out;
    const int* row = ei;
    const int* col = ei + EDGES;

    // workspace layout (4-byte units)
    // [0, N*D)                      : mean (fp32)
    // [N*D, N*D+E)                  : csr_col (int)
    // then deg (N), offsets (N), partial (256), scanned (256)
    size_t need = ((size_t)N_NODES * D + EDGES + 2 * N_NODES + 512) * 4;

    if (ws_size >= need) {
        float* mean    = (float*)d_ws;
        int*   csr_col = (int*)(mean + (size_t)N_NODES * D);
        int*   deg     = csr_col + EDGES;
        int*   offsets = deg + N_NODES;
        int*   partial = offsets + N_NODES;
        int*   scanned = partial + 256;

        hipMemsetAsync(deg, 0, N_NODES * sizeof(int), stream);

        deg_kernel<<<(EDGES + 255) / 256, 256, 0, stream>>>(row, deg);
        chunk_sum_kernel<<<NUM_CHUNKS, SCAN_CHUNK, 0, stream>>>(deg, partial);
        scan_partials_kernel<<<1, SCAN_CHUNK, 0, stream>>>(partial, scanned);
        chunk_scan_kernel<<<NUM_CHUNKS, SCAN_CHUNK, 0, stream>>>(deg, scanned, offsets);
        fill_kernel<<<(EDGES + 255) / 256, 256, 0, stream>>>(row, col, offsets, csr_col);
        gather_mean_kernel<<<(N_NODES * 32 + 255) / 256, 256, 0, stream>>>(
            x, csr_col, offsets, mean);
        gemm_kernel<<<(N_NODES + BM - 1) / BM, 256, 0, stream>>>(x, mean, W, bias, out);
    } else {
        // fallback: atomic scatter (round-1 path)
        float* sum = (float*)d_ws;
        float* cnt = sum + (size_t)N_NODES * D;
        hipMemsetAsync(d_ws, 0, ((size_t)N_NODES * D + N_NODES) * sizeof(float), stream);
        scatter_kernel<<<(EDGES * 32 + 255) / 256, 256, 0, stream>>>(x, row, col, sum, cnt);
        finalize_kernel<<<(N_NODES * 32 + 255) / 256, 256, 0, stream>>>(sum, cnt);
        gemm_kernel<<<(N_NODES + BM - 1) / BM, 256, 0, stream>>>(x, sum, W, bias, out);
    }
}

// Round 3
// 190.825 us; speedup vs baseline: 6.5382x; 1.3133x over previous
//
#include <hip/hip_runtime.h>
#include <hip/hip_bf16.h>

#define N_NODES 50000
#define D 128
#define EDGES 640000
#define SCAN_CHUNK 256
#define NUM_CHUNKS ((N_NODES + SCAN_CHUNK - 1) / SCAN_CHUNK)  // 196

typedef __attribute__((ext_vector_type(8))) __bf16 bf16x8;
typedef __attribute__((ext_vector_type(4))) float f32x4;

// ===========================================================================
// prep: deg count + x -> bf16 (into combined[:, :128]) + W -> bf16
// ===========================================================================
__global__ __launch_bounds__(256) void prep_kernel(
    const float* __restrict__ x, const float* __restrict__ W,
    const int* __restrict__ row, int* __restrict__ deg,
    __bf16* __restrict__ combined, __bf16* __restrict__ Wbf) {
    int tid = blockIdx.x * blockDim.x + threadIdx.x;
    if (tid < EDGES) atomicAdd(&deg[row[tid]], 1);
    if (tid < N_NODES * (D / 8)) {  // 800000 groups of 8 floats
        int base = tid * 8;
        int dst = ((base >> 7) << 8) + (base & 127);  // node*256 + k
        float4 a = *(const float4*)(x + base);
        float4 b = *(const float4*)(x + base + 4);
        bf16x8 v;
        v[0] = (__bf16)a.x; v[1] = (__bf16)a.y; v[2] = (__bf16)a.z; v[3] = (__bf16)a.w;
        v[4] = (__bf16)b.x; v[5] = (__bf16)b.y; v[6] = (__bf16)b.z; v[7] = (__bf16)b.w;
        *(bf16x8*)(combined + dst) = v;
    }
    int wtid = tid - N_NODES * (D / 8);
    if (wtid >= 0 && wtid < 128 * 256 / 8) {  // 4096 groups
        int base = wtid * 8;
        float4 a = *(const float4*)(W + base);
        float4 b = *(const float4*)(W + base + 4);
        bf16x8 v;
        v[0] = (__bf16)a.x; v[1] = (__bf16)a.y; v[2] = (__bf16)a.z; v[3] = (__bf16)a.w;
        v[4] = (__bf16)b.x; v[5] = (__bf16)b.y; v[6] = (__bf16)b.z; v[7] = (__bf16)b.w;
        *(bf16x8*)(Wbf + base) = v;
    }
}

// ===========================================================================
// CSR build: chunked exclusive scan of deg, then fill
// ===========================================================================
__global__ __launch_bounds__(SCAN_CHUNK) void chunk_sum_kernel(
    const int* __restrict__ deg, int* __restrict__ partial) {
    __shared__ int s[SCAN_CHUNK];
    int t = threadIdx.x;
    int i = blockIdx.x * SCAN_CHUNK + t;
    s[t] = (i < N_NODES) ? deg[i] : 0;
    __syncthreads();
    for (int off = SCAN_CHUNK / 2; off > 0; off >>= 1) {
        if (t < off) s[t] += s[t + off];
        __syncthreads();
    }
    if (t == 0) partial[blockIdx.x] = s[0];
}

__global__ __launch_bounds__(SCAN_CHUNK) void scan_partials_kernel(
    const int* __restrict__ partial, int* __restrict__ scanned) {
    __shared__ int s[SCAN_CHUNK];
    int t = threadIdx.x;
    int v = (t < NUM_CHUNKS) ? partial[t] : 0;
    s[t] = v;
    __syncthreads();
    for (int off = 1; off < SCAN_CHUNK; off <<= 1) {
        int add = (t >= off) ? s[t - off] : 0;
        __syncthreads();
        s[t] += add;
        __syncthreads();
    }
    if (t < NUM_CHUNKS) scanned[t] = s[t] - v;  // exclusive
}

__global__ __launch_bounds__(SCAN_CHUNK) void chunk_scan_kernel(
    const int* __restrict__ deg, const int* __restrict__ scanned,
    int* __restrict__ offsets) {
    __shared__ int s[SCAN_CHUNK];
    int t = threadIdx.x;
    int i = blockIdx.x * SCAN_CHUNK + t;
    int v = (i < N_NODES) ? deg[i] : 0;
    s[t] = v;
    __syncthreads();
    for (int off = 1; off < SCAN_CHUNK; off <<= 1) {
        int add = (t >= off) ? s[t - off] : 0;
        __syncthreads();
        s[t] += add;
        __syncthreads();
    }
    if (i < N_NODES) offsets[i] = s[t] - v + scanned[blockIdx.x];
}

// After this, offsets[i] == start of node i+1 (inclusive-scan semantics).
__global__ __launch_bounds__(256) void fill_kernel(
    const int* __restrict__ row, const int* __restrict__ col,
    int* __restrict__ offsets, int* __restrict__ csr_col) {
    int e = blockIdx.x * blockDim.x + threadIdx.x;
    if (e >= EDGES) return;
    int pos = atomicAdd(&offsets[row[e]], 1);
    csr_col[pos] = col[e];
}

// ===========================================================================
// gather: mean over bf16 x rows -> combined[:, 128:256] (bf16)
// 16 threads per node, bf16x8 (16 B) per thread.
// ===========================================================================
__global__ __launch_bounds__(256) void gather_mean_kernel(
    __bf16* combined, const int* __restrict__ csr_col,
    const int* __restrict__ offsets) {
    int tid = blockIdx.x * blockDim.x + threadIdx.x;
    int node = tid >> 4;
    int part = tid & 15;
    if (node >= N_NODES) return;
    int start = (node == 0) ? 0 : offsets[node - 1];
    int end = offsets[node];
    float acc[8] = {};
    int c_next = (start < end) ? csr_col[start] : 0;
    for (int e = start; e < end; ++e) {
        int c = c_next;
        if (e + 1 < end) c_next = csr_col[e + 1];
        bf16x8 v = *(const bf16x8*)(combined + (size_t)c * 256 + part * 8);
        #pragma unroll
        for (int j = 0; j < 8; ++j) acc[j] += (float)v[j];
    }
    float inv = 1.0f / ((float)(end - start) + 1e-8f);
    bf16x8 o;
    #pragma unroll
    for (int j = 0; j < 8; ++j) o[j] = (__bf16)(acc[j] * inv);
    *(bf16x8*)(combined + (size_t)node * 256 + 128 + part * 8) = o;
}

// ===========================================================================
// MFMA GEMM: out = relu(combined[N,256] @ Wbf[128,256]^T + b), fp32 out.
// Block: 256 threads = 4 waves in 2x2; tile 128 rows x 128 cols; BK=32.
// Each wave: 4x4 grid of 16x16x32 MFMA tiles (64x64 region).
// ===========================================================================
__global__ __launch_bounds__(256) void gemm_mfma_kernel(
    const __bf16* __restrict__ A,   // combined [N][256]
    const __bf16* __restrict__ Bw,  // Wbf [128][256]
    const float* __restrict__ bias,
    float* __restrict__ out) {
    __shared__ __bf16 As[128][40];  // stride 40 -> 2-way LDS aliasing only (free)
    __shared__ __bf16 Bs[128][40];
    int t = threadIdx.x;
    int lane = t & 63;
    int wid = t >> 6;
    int wm = wid >> 1, wn = wid & 1;
    int block_row = blockIdx.x * 128;
    int fr = lane & 15;
    int kg = (lane >> 4) * 8;

    f32x4 acc[4][4] = {};

    for (int k0 = 0; k0 < 256; k0 += 32) {
        int r = t >> 2;
        int kk = (t & 3) * 8;
        #pragma unroll
        for (int p = 0; p < 2; ++p) {
            int row = r + p * 64;
            int node = block_row + row;
            if (node >= N_NODES) node = N_NODES - 1;  // stores guarded later
            *(bf16x8*)&As[row][kk] = *(const bf16x8*)(A + (size_t)node * 256 + k0 + kk);
            *(bf16x8*)&Bs[row][kk] = *(const bf16x8*)(Bw + (size_t)row * 256 + k0 + kk);
        }
        __syncthreads();
        bf16x8 af[4], bfr[4];
        #pragma unroll
        for (int i = 0; i < 4; ++i) {
            af[i]  = *(const bf16x8*)&As[wm * 64 + i * 16 + fr][kg];
            bfr[i] = *(const bf16x8*)&Bs[wn * 64 + i * 16 + fr][kg];
        }
        #pragma unroll
        for (int mi = 0; mi < 4; ++mi)
            #pragma unroll
            for (int ni = 0; ni < 4; ++ni)
                acc[mi][ni] = __builtin_amdgcn_mfma_f32_16x16x32_bf16(
                    af[mi], bfr[ni], acc[mi][ni], 0, 0, 0);
        __syncthreads();
    }

    // Epilogue. C/D layout: col = lane&15, row = (lane>>4)*4 + reg.
    #pragma unroll
    for (int ni = 0; ni < 4; ++ni) {
        int col = wn * 64 + ni * 16 + fr;
        float bv = bias[col];
        #pragma unroll
        for (int mi = 0; mi < 4; ++mi) {
            int row_base = block_row + wm * 64 + mi * 16 + (lane >> 4) * 4;
            #pragma unroll
            for (int r2 = 0; r2 < 4; ++r2) {
                int row = row_base + r2;
                if (row < N_NODES)
                    out[(size_t)row * 128 + col] = fmaxf(acc[mi][ni][r2] + bv, 0.0f);
            }
        }
    }
}

// ===========================================================================
// Fallback path (fp32 atomic scatter + fp32 gemm) if ws too small
// ===========================================================================
__global__ __launch_bounds__(256) void scatter_kernel(
    const float* __restrict__ x, const int* __restrict__ row,
    const int* __restrict__ col, float* __restrict__ sum,
    float* __restrict__ cnt) {
    int tid = blockIdx.x * blockDim.x + threadIdx.x;
    int e = tid >> 5;
    int part = tid & 31;
    if (e >= EDGES) return;
    int r = row[e];
    int c = col[e];
    float4 v = ((const float4*)(x + (size_t)c * D))[part];
    float* dst = sum + (size_t)r * D + part * 4;
    atomicAdd(dst + 0, v.x);
    atomicAdd(dst + 1, v.y);
    atomicAdd(dst + 2, v.z);
    atomicAdd(dst + 3, v.w);
    if (part == 0) atomicAdd(cnt + r, 1.0f);
}

__global__ __launch_bounds__(256) void finalize_kernel(
    float* __restrict__ sum, const float* __restrict__ cnt) {
    int i = blockIdx.x * blockDim.x + threadIdx.x;
    if (i >= N_NODES * (D / 4)) return;
    int node = i >> 5;
    float inv = 1.0f / (cnt[node] + 1e-8f);
    float4* p = (float4*)sum;
    float4 v = p[i];
    v.x *= inv; v.y *= inv; v.z *= inv; v.w *= inv;
    p[i] = v;
}

__global__ __launch_bounds__(256) void gemm_kernel(
    const float* __restrict__ x, const float* __restrict__ mean,
    const float* __restrict__ W, const float* __restrict__ bias,
    float* __restrict__ out) {
    __shared__ float As[16][64];
    __shared__ float Bs[16][128];
    int t = threadIdx.x;
    int tx = t & 31;
    int ty = t >> 5;
    int block_row = blockIdx.x * 64;
    float acc[8][4] = {};
    for (int k0 = 0; k0 < 2 * D; k0 += 16) {
        {
            int m = t >> 2;
            int kk = (t & 3) * 4;
            int node = block_row + m;
            if (node >= N_NODES) node = N_NODES - 1;
            int kgl = k0 + kk;
            const float* src = (kgl < D) ? (x + (size_t)node * D + kgl)
                                         : (mean + (size_t)node * D + (kgl - D));
            float4 v = *(const float4*)src;
            As[kk + 0][m] = v.x; As[kk + 1][m] = v.y;
            As[kk + 2][m] = v.z; As[kk + 3][m] = v.w;
        }
        {
            int n = t >> 1;
            int kk = (t & 1) * 8;
            const float* src = W + (size_t)n * (2 * D) + k0 + kk;
            float4 v0 = *(const float4*)src;
            float4 v1 = *(const float4*)(src + 4);
            Bs[kk + 0][n] = v0.x; Bs[kk + 1][n] = v0.y;
            Bs[kk + 2][n] = v0.z; Bs[kk + 3][n] = v0.w;
            Bs[kk + 4][n] = v1.x; Bs[kk + 5][n] = v1.y;
            Bs[kk + 6][n] = v1.z; Bs[kk + 7][n] = v1.w;
        }
        __syncthreads();
        #pragma unroll
        for (int kk = 0; kk < 16; ++kk) {
            float a[8], bv[4];
            #pragma unroll
            for (int i = 0; i < 8; ++i) a[i] = As[kk][ty * 8 + i];
            #pragma unroll
            for (int j = 0; j < 4; ++j) bv[j] = Bs[kk][tx * 4 + j];
            #pragma unroll
            for (int i = 0; i < 8; ++i)
                #pragma unroll
                for (int j = 0; j < 4; ++j)
                    acc[i][j] += a[i] * bv[j];
        }
        __syncthreads();
    }
    float bv[4];
    #pragma unroll
    for (int j = 0; j < 4; ++j) bv[j] = bias[tx * 4 + j];
    #pragma unroll
    for (int i = 0; i < 8; ++i) {
        int node = block_row + ty * 8 + i;
        if (node < N_NODES) {
            float4 o;
            o.x = fmaxf(acc[i][0] + bv[0], 0.0f);
            o.y = fmaxf(acc[i][1] + bv[1], 0.0f);
            o.z = fmaxf(acc[i][2] + bv[2], 0.0f);
            o.w = fmaxf(acc[i][3] + bv[3], 0.0f);
            *(float4*)(out + (size_t)node * D + tx * 4) = o;
        }
    }
}

extern "C" void kernel_launch(void* const* d_in, const int* in_sizes, int n_in,
                              void* d_out, int out_size, void* d_ws, size_t ws_size,
                              hipStream_t stream) {
    const float* x    = (const float*)d_in[0];
    const int*   ei   = (const int*)d_in[1];  // [2, E] int32
    const float* W    = (const float*)d_in[2];
    const float* bias = (const float*)d_in[3];
    float* out = (float*)d_out;
    const int* row = ei;
    const int* col = ei + EDGES;

    // ws layout (bytes):
    //   combined : N*256 bf16   = 25,600,000
    //   Wbf      : 128*256 bf16 = 65,536
    //   csr_col  : E int        = 2,560,000
    //   deg      : N int
    //   offsets  : N int
    //   partial  : 256 int
    //   scanned  : 256 int
    size_t need = (size_t)N_NODES * 256 * 2 + 128 * 256 * 2 +
                  (size_t)EDGES * 4 + (size_t)N_NODES * 4 * 2 + 512 * 4;

    if (ws_size >= need) {
        __bf16* combined = (__bf16*)d_ws;
        __bf16* Wbf      = combined + (size_t)N_NODES * 256;
        int* csr_col = (int*)(Wbf + 128 * 256);
        int* deg     = csr_col + EDGES;
        int* offsets = deg + N_NODES;
        int* partial = offsets + N_NODES;
        int* scanned = partial + 256;

        hipMemsetAsync(deg, 0, N_NODES * sizeof(int), stream);

        int prep_threads = N_NODES * (D / 8) + 128 * 256 / 8;  // 804096
        prep_kernel<<<(prep_threads + 255) / 256, 256, 0, stream>>>(
            x, W, row, deg, combined, Wbf);
        chunk_sum_kernel<<<NUM_CHUNKS, SCAN_CHUNK, 0, stream>>>(deg, partial);
        scan_partials_kernel<<<1, SCAN_CHUNK, 0, stream>>>(partial, scanned);
        chunk_scan_kernel<<<NUM_CHUNKS, SCAN_CHUNK, 0, stream>>>(deg, scanned, offsets);
        fill_kernel<<<(EDGES + 255) / 256, 256, 0, stream>>>(row, col, offsets, csr_col);
        gather_mean_kernel<<<(N_NODES * 16 + 255) / 256, 256, 0, stream>>>(
            combined, csr_col, offsets);
        gemm_mfma_kernel<<<(N_NODES + 127) / 128, 256, 0, stream>>>(
            combined, Wbf, bias, out);
    } else {
        float* sum = (float*)d_ws;
        float* cnt = sum + (size_t)N_NODES * D;
        hipMemsetAsync(d_ws, 0, ((size_t)N_NODES * D + N_NODES) * sizeof(float), stream);
        scatter_kernel<<<(EDGES * 32 + 255) / 256, 256, 0, stream>>>(x, row, col, sum, cnt);
        finalize_kernel<<<(N_NODES * 32 + 255) / 256, 256, 0, stream>>>(sum, cnt);
        gemm_kernel<<<(N_NODES + 63) / 64, 256, 0, stream>>>(x, sum, W, bias, out);
    }
}

// Round 4
// 180.297 us; speedup vs baseline: 6.9199x; 1.0584x over previous
//
#include <hip/hip_runtime.h>
#include <hip/hip_bf16.h>

#define N_NODES 50000
#define D 128
#define EDGES 640000
#define SCAN_CHUNK 256
#define NUM_CHUNKS ((N_NODES + SCAN_CHUNK - 1) / SCAN_CHUNK)  // 196

typedef __attribute__((ext_vector_type(8))) __bf16 bf16x8;
typedef __attribute__((ext_vector_type(4))) float f32x4;
typedef __attribute__((ext_vector_type(2))) float f32x2;

// ===========================================================================
// prep: deg count + x -> bf16 (combined[:, :128]) + x -> fp8 e4m3 (x8)
//       + W -> bf16
// ===========================================================================
__global__ __launch_bounds__(256) void prep_kernel(
    const float* __restrict__ x, const float* __restrict__ W,
    const int* __restrict__ row, int* __restrict__ deg,
    __bf16* __restrict__ combined, __bf16* __restrict__ Wbf,
    int2* __restrict__ x8) {
    int tid = blockIdx.x * blockDim.x + threadIdx.x;
    if (tid < EDGES) atomicAdd(&deg[row[tid]], 1);
    if (tid < N_NODES * (D / 8)) {  // 800000 groups of 8 floats
        int base = tid * 8;
        int dst = ((base >> 7) << 8) + (base & 127);  // node*256 + k
        float4 a = *(const float4*)(x + base);
        float4 b = *(const float4*)(x + base + 4);
        bf16x8 v;
        v[0] = (__bf16)a.x; v[1] = (__bf16)a.y; v[2] = (__bf16)a.z; v[3] = (__bf16)a.w;
        v[4] = (__bf16)b.x; v[5] = (__bf16)b.y; v[6] = (__bf16)b.z; v[7] = (__bf16)b.w;
        *(bf16x8*)(combined + dst) = v;
        // fp8 e4m3 (OCP on gfx950): byte j of row = feature j
        int w0 = __builtin_amdgcn_cvt_pk_fp8_f32(a.x, a.y, 0, false);
        w0 = __builtin_amdgcn_cvt_pk_fp8_f32(a.z, a.w, w0, true);
        int w1 = __builtin_amdgcn_cvt_pk_fp8_f32(b.x, b.y, 0, false);
        w1 = __builtin_amdgcn_cvt_pk_fp8_f32(b.z, b.w, w1, true);
        x8[tid] = make_int2(w0, w1);
    }
    int wtid = tid - N_NODES * (D / 8);
    if (wtid >= 0 && wtid < 128 * 256 / 8) {  // 4096 groups
        int base = wtid * 8;
        float4 a = *(const float4*)(W + base);
        float4 b = *(const float4*)(W + base + 4);
        bf16x8 v;
        v[0] = (__bf16)a.x; v[1] = (__bf16)a.y; v[2] = (__bf16)a.z; v[3] = (__bf16)a.w;
        v[4] = (__bf16)b.x; v[5] = (__bf16)b.y; v[6] = (__bf16)b.z; v[7] = (__bf16)b.w;
        *(bf16x8*)(Wbf + base) = v;
    }
}

// ===========================================================================
// CSR build: chunked exclusive scan of deg, then fill
// ===========================================================================
__global__ __launch_bounds__(SCAN_CHUNK) void chunk_sum_kernel(
    const int* __restrict__ deg, int* __restrict__ partial) {
    __shared__ int s[SCAN_CHUNK];
    int t = threadIdx.x;
    int i = blockIdx.x * SCAN_CHUNK + t;
    s[t] = (i < N_NODES) ? deg[i] : 0;
    __syncthreads();
    for (int off = SCAN_CHUNK / 2; off > 0; off >>= 1) {
        if (t < off) s[t] += s[t + off];
        __syncthreads();
    }
    if (t == 0) partial[blockIdx.x] = s[0];
}

__global__ __launch_bounds__(SCAN_CHUNK) void scan_partials_kernel(
    const int* __restrict__ partial, int* __restrict__ scanned) {
    __shared__ int s[SCAN_CHUNK];
    int t = threadIdx.x;
    int v = (t < NUM_CHUNKS) ? partial[t] : 0;
    s[t] = v;
    __syncthreads();
    for (int off = 1; off < SCAN_CHUNK; off <<= 1) {
        int add = (t >= off) ? s[t - off] : 0;
        __syncthreads();
        s[t] += add;
        __syncthreads();
    }
    if (t < NUM_CHUNKS) scanned[t] = s[t] - v;  // exclusive
}

__global__ __launch_bounds__(SCAN_CHUNK) void chunk_scan_kernel(
    const int* __restrict__ deg, const int* __restrict__ scanned,
    int* __restrict__ offsets) {
    __shared__ int s[SCAN_CHUNK];
    int t = threadIdx.x;
    int i = blockIdx.x * SCAN_CHUNK + t;
    int v = (i < N_NODES) ? deg[i] : 0;
    s[t] = v;
    __syncthreads();
    for (int off = 1; off < SCAN_CHUNK; off <<= 1) {
        int add = (t >= off) ? s[t - off] : 0;
        __syncthreads();
        s[t] += add;
        __syncthreads();
    }
    if (i < N_NODES) offsets[i] = s[t] - v + scanned[blockIdx.x];
}

// After this, offsets[i] == start of node i+1 (inclusive-scan semantics).
__global__ __launch_bounds__(256) void fill_kernel(
    const int* __restrict__ row, const int* __restrict__ col,
    int* __restrict__ offsets, int* __restrict__ csr_col) {
    int e = blockIdx.x * blockDim.x + threadIdx.x;
    if (e >= EDGES) return;
    int pos = atomicAdd(&offsets[row[e]], 1);
    csr_col[pos] = col[e];
}

// ===========================================================================
// gather: mean over fp8 x rows -> combined[:, 128:256] (bf16)
// 8 threads per node; each lane loads int4 = 16 fp8 features per edge.
// ===========================================================================
#define ACC4(q, off)                                                  \
    {                                                                 \
        f32x2 p0 = __builtin_amdgcn_cvt_pk_f32_fp8((q), false);       \
        f32x2 p1 = __builtin_amdgcn_cvt_pk_f32_fp8((q), true);        \
        acc[(off) + 0] += p0[0]; acc[(off) + 1] += p0[1];             \
        acc[(off) + 2] += p1[0]; acc[(off) + 3] += p1[1];             \
    }

__global__ __launch_bounds__(256) void gather_mean_kernel(
    const int4* __restrict__ x8, const int* __restrict__ csr_col,
    const int* __restrict__ offsets, __bf16* __restrict__ combined) {
    int tid = blockIdx.x * blockDim.x + threadIdx.x;
    int node = tid >> 3;
    int part = tid & 7;
    if (node >= N_NODES) return;
    int start = (node == 0) ? 0 : offsets[node - 1];
    int end = offsets[node];
    float acc[16] = {};
    int e = start;
    for (; e + 2 <= end; e += 2) {
        int c0 = csr_col[e];
        int c1 = csr_col[e + 1];
        int4 v0 = x8[c0 * 8 + part];
        int4 v1 = x8[c1 * 8 + part];
        ACC4(v0.x, 0); ACC4(v0.y, 4); ACC4(v0.z, 8); ACC4(v0.w, 12);
        ACC4(v1.x, 0); ACC4(v1.y, 4); ACC4(v1.z, 8); ACC4(v1.w, 12);
    }
    if (e < end) {
        int c = csr_col[e];
        int4 v = x8[c * 8 + part];
        ACC4(v.x, 0); ACC4(v.y, 4); ACC4(v.z, 8); ACC4(v.w, 12);
    }
    float inv = 1.0f / ((float)(end - start) + 1e-8f);
    bf16x8 o0, o1;
    #pragma unroll
    for (int j = 0; j < 8; ++j) {
        o0[j] = (__bf16)(acc[j] * inv);
        o1[j] = (__bf16)(acc[8 + j] * inv);
    }
    __bf16* dst = combined + (size_t)node * 256 + 128 + part * 16;
    *(bf16x8*)dst = o0;
    *(bf16x8*)(dst + 8) = o1;
}

// ===========================================================================
// MFMA GEMM: out = relu(combined[N,256] @ Wbf[128,256]^T + b), fp32 out.
// ===========================================================================
__global__ __launch_bounds__(256) void gemm_mfma_kernel(
    const __bf16* __restrict__ A,   // combined [N][256]
    const __bf16* __restrict__ Bw,  // Wbf [128][256]
    const float* __restrict__ bias,
    float* __restrict__ out) {
    __shared__ __bf16 As[128][40];  // stride 40 -> 2-way LDS aliasing only (free)
    __shared__ __bf16 Bs[128][40];
    int t = threadIdx.x;
    int lane = t & 63;
    int wid = t >> 6;
    int wm = wid >> 1, wn = wid & 1;
    int block_row = blockIdx.x * 128;
    int fr = lane & 15;
    int kg = (lane >> 4) * 8;

    f32x4 acc[4][4] = {};

    for (int k0 = 0; k0 < 256; k0 += 32) {
        int r = t >> 2;
        int kk = (t & 3) * 8;
        #pragma unroll
        for (int p = 0; p < 2; ++p) {
            int row = r + p * 64;
            int node = block_row + row;
            if (node >= N_NODES) node = N_NODES - 1;  // stores guarded later
            *(bf16x8*)&As[row][kk] = *(const bf16x8*)(A + (size_t)node * 256 + k0 + kk);
            *(bf16x8*)&Bs[row][kk] = *(const bf16x8*)(Bw + (size_t)row * 256 + k0 + kk);
        }
        __syncthreads();
        bf16x8 af[4], bfr[4];
        #pragma unroll
        for (int i = 0; i < 4; ++i) {
            af[i]  = *(const bf16x8*)&As[wm * 64 + i * 16 + fr][kg];
            bfr[i] = *(const bf16x8*)&Bs[wn * 64 + i * 16 + fr][kg];
        }
        #pragma unroll
        for (int mi = 0; mi < 4; ++mi)
            #pragma unroll
            for (int ni = 0; ni < 4; ++ni)
                acc[mi][ni] = __builtin_amdgcn_mfma_f32_16x16x32_bf16(
                    af[mi], bfr[ni], acc[mi][ni], 0, 0, 0);
        __syncthreads();
    }

    // C/D layout: col = lane&15, row = (lane>>4)*4 + reg.
    #pragma unroll
    for (int ni = 0; ni < 4; ++ni) {
        int col = wn * 64 + ni * 16 + fr;
        float bv = bias[col];
        #pragma unroll
        for (int mi = 0; mi < 4; ++mi) {
            int row_base = block_row + wm * 64 + mi * 16 + (lane >> 4) * 4;
            #pragma unroll
            for (int r2 = 0; r2 < 4; ++r2) {
                int row = row_base + r2;
                if (row < N_NODES)
                    out[(size_t)row * 128 + col] = fmaxf(acc[mi][ni][r2] + bv, 0.0f);
            }
        }
    }
}

// ===========================================================================
// Fallback path (fp32 atomic scatter + fp32 gemm) if ws too small
// ===========================================================================
__global__ __launch_bounds__(256) void scatter_kernel(
    const float* __restrict__ x, const int* __restrict__ row,
    const int* __restrict__ col, float* __restrict__ sum,
    float* __restrict__ cnt) {
    int tid = blockIdx.x * blockDim.x + threadIdx.x;
    int e = tid >> 5;
    int part = tid & 31;
    if (e >= EDGES) return;
    int r = row[e];
    int c = col[e];
    float4 v = ((const float4*)(x + (size_t)c * D))[part];
    float* dst = sum + (size_t)r * D + part * 4;
    atomicAdd(dst + 0, v.x);
    atomicAdd(dst + 1, v.y);
    atomicAdd(dst + 2, v.z);
    atomicAdd(dst + 3, v.w);
    if (part == 0) atomicAdd(cnt + r, 1.0f);
}

__global__ __launch_bounds__(256) void finalize_kernel(
    float* __restrict__ sum, const float* __restrict__ cnt) {
    int i = blockIdx.x * blockDim.x + threadIdx.x;
    if (i >= N_NODES * (D / 4)) return;
    int node = i >> 5;
    float inv = 1.0f / (cnt[node] + 1e-8f);
    float4* p = (float4*)sum;
    float4 v = p[i];
    v.x *= inv; v.y *= inv; v.z *= inv; v.w *= inv;
    p[i] = v;
}

__global__ __launch_bounds__(256) void gemm_kernel(
    const float* __restrict__ x, const float* __restrict__ mean,
    const float* __restrict__ W, const float* __restrict__ bias,
    float* __restrict__ out) {
    __shared__ float As[16][64];
    __shared__ float Bs[16][128];
    int t = threadIdx.x;
    int tx = t & 31;
    int ty = t >> 5;
    int block_row = blockIdx.x * 64;
    float acc[8][4] = {};
    for (int k0 = 0; k0 < 2 * D; k0 += 16) {
        {
            int m = t >> 2;
            int kk = (t & 3) * 4;
            int node = block_row + m;
            if (node >= N_NODES) node = N_NODES - 1;
            int kgl = k0 + kk;
            const float* src = (kgl < D) ? (x + (size_t)node * D + kgl)
                                         : (mean + (size_t)node * D + (kgl - D));
            float4 v = *(const float4*)src;
            As[kk + 0][m] = v.x; As[kk + 1][m] = v.y;
            As[kk + 2][m] = v.z; As[kk + 3][m] = v.w;
        }
        {
            int n = t >> 1;
            int kk = (t & 1) * 8;
            const float* src = W + (size_t)n * (2 * D) + k0 + kk;
            float4 v0 = *(const float4*)src;
            float4 v1 = *(const float4*)(src + 4);
            Bs[kk + 0][n] = v0.x; Bs[kk + 1][n] = v0.y;
            Bs[kk + 2][n] = v0.z; Bs[kk + 3][n] = v0.w;
            Bs[kk + 4][n] = v1.x; Bs[kk + 5][n] = v1.y;
            Bs[kk + 6][n] = v1.z; Bs[kk + 7][n] = v1.w;
        }
        __syncthreads();
        #pragma unroll
        for (int kk = 0; kk < 16; ++kk) {
            float a[8], bv[4];
            #pragma unroll
            for (int i = 0; i < 8; ++i) a[i] = As[kk][ty * 8 + i];
            #pragma unroll
            for (int j = 0; j < 4; ++j) bv[j] = Bs[kk][tx * 4 + j];
            #pragma unroll
            for (int i = 0; i < 8; ++i)
                #pragma unroll
                for (int j = 0; j < 4; ++j)
                    acc[i][j] += a[i] * bv[j];
        }
        __syncthreads();
    }
    float bv[4];
    #pragma unroll
    for (int j = 0; j < 4; ++j) bv[j] = bias[tx * 4 + j];
    #pragma unroll
    for (int i = 0; i < 8; ++i) {
        int node = block_row + ty * 8 + i;
        if (node < N_NODES) {
            float4 o;
            o.x = fmaxf(acc[i][0] + bv[0], 0.0f);
            o.y = fmaxf(acc[i][1] + bv[1], 0.0f);
            o.z = fmaxf(acc[i][2] + bv[2], 0.0f);
            o.w = fmaxf(acc[i][3] + bv[3], 0.0f);
            *(float4*)(out + (size_t)node * D + tx * 4) = o;
        }
    }
}

extern "C" void kernel_launch(void* const* d_in, const int* in_sizes, int n_in,
                              void* d_out, int out_size, void* d_ws, size_t ws_size,
                              hipStream_t stream) {
    const float* x    = (const float*)d_in[0];
    const int*   ei   = (const int*)d_in[1];  // [2, E] int32
    const float* W    = (const float*)d_in[2];
    const float* bias = (const float*)d_in[3];
    float* out = (float*)d_out;
    const int* row = ei;
    const int* col = ei + EDGES;

    // ws layout (bytes):
    //   combined : N*256 bf16   = 25,600,000
    //   Wbf      : 128*256 bf16 = 65,536
    //   x8       : N*128 fp8    =  6,400,000
    //   csr_col  : E int        =  2,560,000
    //   deg, offsets : N int each
    //   partial, scanned : 256 int each
    size_t need = (size_t)N_NODES * 256 * 2 + 128 * 256 * 2 +
                  (size_t)N_NODES * 128 + (size_t)EDGES * 4 +
                  (size_t)N_NODES * 4 * 2 + 512 * 4;

    if (ws_size >= need) {
        __bf16* combined = (__bf16*)d_ws;
        __bf16* Wbf      = combined + (size_t)N_NODES * 256;
        int2* x8     = (int2*)(Wbf + 128 * 256);
        int* csr_col = (int*)(x8 + (size_t)N_NODES * (D / 8));
        int* deg     = csr_col + EDGES;
        int* offsets = deg + N_NODES;
        int* partial = offsets + N_NODES;
        int* scanned = partial + 256;

        hipMemsetAsync(deg, 0, N_NODES * sizeof(int), stream);

        int prep_threads = N_NODES * (D / 8) + 128 * 256 / 8;  // 804096
        prep_kernel<<<(prep_threads + 255) / 256, 256, 0, stream>>>(
            x, W, row, deg, combined, Wbf, x8);
        chunk_sum_kernel<<<NUM_CHUNKS, SCAN_CHUNK, 0, stream>>>(deg, partial);
        scan_partials_kernel<<<1, SCAN_CHUNK, 0, stream>>>(partial, scanned);
        chunk_scan_kernel<<<NUM_CHUNKS, SCAN_CHUNK, 0, stream>>>(deg, scanned, offsets);
        fill_kernel<<<(EDGES + 255) / 256, 256, 0, stream>>>(row, col, offsets, csr_col);
        gather_mean_kernel<<<(N_NODES * 8 + 255) / 256, 256, 0, stream>>>(
            (const int4*)x8, csr_col, offsets, combined);
        gemm_mfma_kernel<<<(N_NODES + 127) / 128, 256, 0, stream>>>(
            combined, Wbf, bias, out);
    } else {
        float* sum = (float*)d_ws;
        float* cnt = sum + (size_t)N_NODES * D;
        hipMemsetAsync(d_ws, 0, ((size_t)N_NODES * D + N_NODES) * sizeof(float), stream);
        scatter_kernel<<<(EDGES * 32 + 255) / 256, 256, 0, stream>>>(x, row, col, sum, cnt);
        finalize_kernel<<<(N_NODES * 32 + 255) / 256, 256, 0, stream>>>(sum, cnt);
        gemm_kernel<<<(N_NODES + 63) / 64, 256, 0, stream>>>(x, sum, W, bias, out);
    }
}